// Round 18
// baseline (1096.089 us; speedup 1.0000x reference)
//
#include <hip/hip_runtime.h>
#include <hip/hip_bf16.h>
#include <math.h>

#define NROWS   262144
#define ABM     128                                     // attn rows/block
#define FBM     128                                     // ffn rows/block
#define ATHREADS 512
#define FTHREADS 512
#define LDSB_A  (65536 + 65536 + 4096 + 8192 + 1024)    // attn: 141K, 1 block/CU
#define LDSB_B  (65536 + 65536)                         // ffn: Cbuf 64K + Hbuf 64K

using bf16x8 = __attribute__((ext_vector_type(8))) short;
using s16x4  = __attribute__((ext_vector_type(4))) short;
using f32x4  = __attribute__((ext_vector_type(4))) float;

__device__ __forceinline__ short f2bf(float f) {
  __hip_bfloat16 h = __float2bfloat16(f);
  return __builtin_bit_cast(short, h);
}
__device__ __forceinline__ float bf2f(short s) {
  __hip_bfloat16 h = __builtin_bit_cast(__hip_bfloat16, s);
  return __bfloat162float(h);
}
__device__ __forceinline__ unsigned pack2(float a, float b) {
  return (unsigned)(unsigned short)f2bf(a) | ((unsigned)(unsigned short)f2bf(b) << 16);
}
// XOR-swizzled byte offset into a bf16 LDS tile with row stride RSTR bytes
template <int RSTR>
__device__ __forceinline__ int swzR(int row, int col) {
  return row * RSTR + ((col * 2) ^ ((row & 7) << 4));
}
__device__ __forceinline__ int swz(int row, int col) {   // 256-col tile (512B rows)
  return swzR<512>(row, col);
}

__device__ __forceinline__ float red16(float p) {
  p += __shfl_xor(p, 1, 64);
  p += __shfl_xor(p, 2, 64);
  p += __shfl_xor(p, 4, 64);
  p += __shfl_xor(p, 8, 64);
  return p;
}

// C[MF*16 rows x NF*16 cols] += A_lds @ WT[cols][Kw] (B pre-transposed bf16)
template <int MF, int NF, int KLEN = 256, int RSTR = 512>
__device__ __forceinline__ void gemmT(const char* __restrict__ Abuf,
                                      const short* __restrict__ WT, int Kw,
                                      int col0, int koff, int li, int hi,
                                      f32x4 (&acc)[MF][NF]) {
  const short* wp[NF];
#pragma unroll
  for (int n = 0; n < NF; ++n)
    wp[n] = WT + (size_t)(col0 + 16 * n + li) * Kw + koff + hi * 8;
#pragma unroll 2
  for (int kk = 0; kk < KLEN; kk += 32) {
    int ka = kk + hi * 8;
    bf16x8 b[NF];
#pragma unroll
    for (int n = 0; n < NF; ++n) b[n] = *(const bf16x8*)(wp[n] + kk);
    bf16x8 a[MF];
#pragma unroll
    for (int m = 0; m < MF; ++m)
      a[m] = *(const bf16x8*)(Abuf + swzR<RSTR>(16 * m + li, ka));
#pragma unroll
    for (int m = 0; m < MF; ++m)
#pragma unroll
      for (int n = 0; n < NF; ++n)
        acc[m][n] = __builtin_amdgcn_mfma_f32_16x16x32_bf16(a[m], b[n], acc[m][n], 0, 0, 0);
  }
}

// transpose + bf16-convert all weights (Wq pre-scaled by 1/sqrt(DH)):
// WqT,WkT,WvT,WoT: [256][256]; W1T: [1024][256]; W2T: [256][1024]
__global__ void prep(const float* __restrict__ Wq, const float* __restrict__ Wk,
                     const float* __restrict__ Wv, const float* __restrict__ Wo,
                     const float* __restrict__ W1, const float* __restrict__ W2,
                     short* __restrict__ wt) {
  int idx = blockIdx.x * blockDim.x + threadIdx.x;  // 0..786431
  if (idx < 262144) {
    int m = idx >> 16;
    const float* W = (m == 0) ? Wq : (m == 1) ? Wk : (m == 2) ? Wv : Wo;
    float s = (m == 0) ? 0.17677669529663687f : 1.0f;
    int l = idx & 65535;
    int n = l >> 8, k = l & 255;
    wt[idx] = f2bf(W[k * 256 + n] * s);
  } else if (idx < 524288) {
    int l = idx - 262144;
    int n = l >> 8, k = l & 255;
    wt[idx] = f2bf(W1[k * 1024 + n]);
  } else {
    int l = idx - 524288;
    int n = l >> 10, k = l & 1023;
    wt[idx] = f2bf(W2[k * 256 + n]);
  }
}

// ================= kernel A: attention + O-proj + LN1 -> h (bf16) =================
// BM=128, 512 threads / 8 waves; wave w owns head w (32 cols), MF=8, NF=2.
__global__ __launch_bounds__(ATHREADS, 2)
void attn_ln1(const float* __restrict__ x, const float* __restrict__ sx,
              const float* __restrict__ dx,
              const float* __restrict__ bq, const float* __restrict__ bv,
              const float* __restrict__ bo,
              const float* __restrict__ g1, const float* __restrict__ be1,
              const short* __restrict__ wt, short* __restrict__ hout) {
  extern __shared__ char sm[];
  char*  Cbuf = sm;                        // x tile [128][256] (persistent) -> h
  char*  Tbuf = sm + 65536;                // dst -> src -> ctx
  float* sc   = (float*)(sm + 131072);     // [8 waves][128 rows] scores/weights (4K)
  float* scrP = (float*)(sm + 135168);     // LN1 partials [8][128][2] (8K)
  float* scrM = (float*)(sm + 143360);     // LN1 mean/rstd [128][2] (1K)

  const short* WqT = wt;
  const short* WkT = wt + 65536;
  const short* WvT = wt + 131072;
  const short* WoT = wt + 196608;

  const int tid  = threadIdx.x;
  const int w    = tid >> 6;               // 0..7 (= head)
  const int lane = tid & 63;
  const int li   = lane & 15;
  const int hi   = lane >> 4;
  const int cw   = w * 32;                 // wave col slice (1 head)
  const size_t row0 = (size_t)blockIdx.x * ABM;

  const float* xt = x  + row0 * 256;
  const float* st = sx + row0 * 256;
  const float* dt = dx + row0 * 256;

  float4 ld[16];

  // ---- P0: stage x -> Cbuf (persistent) ----
#pragma unroll
  for (int it = 0; it < 16; ++it) {
    int idx = it * ATHREADS + tid;         // 0..8191 float4 slots
    ld[it] = *(const float4*)(xt + (idx >> 6) * 256 + ((idx & 63) << 2));
  }
#pragma unroll
  for (int it = 0; it < 16; ++it) {
    int idx = it * ATHREADS + tid;
    int r = idx >> 6, c = (idx & 63) << 2;
    s16x4 o;
    o[0] = f2bf(ld[it].x); o[1] = f2bf(ld[it].y);
    o[2] = f2bf(ld[it].z); o[3] = f2bf(ld[it].w);
    *(s16x4*)(Cbuf + swz(r, c)) = o;
  }
  __syncthreads();

  // ---- P1: issue dst loads; Q gemm (Cbuf); pack q->bf16; write dst->Tbuf ----
#pragma unroll
  for (int it = 0; it < 16; ++it) {
    int idx = it * ATHREADS + tid;
    ld[it] = *(const float4*)(dt + (idx >> 6) * 256 + ((idx & 63) << 2));
  }
  unsigned qb[8][2][2];
  {
    f32x4 qa[8][2];
#pragma unroll
    for (int m = 0; m < 8; ++m)
#pragma unroll
      for (int n = 0; n < 2; ++n) qa[m][n] = (f32x4){0.f, 0.f, 0.f, 0.f};
    gemmT<8, 2>(Cbuf, WqT, 256, cw, 0, li, hi, qa);
    const float scl = 0.17677669529663687f;
#pragma unroll
    for (int n = 0; n < 2; ++n) {
      float bqn = bq[cw + 16 * n + li] * scl;
#pragma unroll
      for (int m = 0; m < 8; ++m) {
        qb[m][n][0] = pack2(qa[m][n][0] + bqn, qa[m][n][1] + bqn);
        qb[m][n][1] = pack2(qa[m][n][2] + bqn, qa[m][n][3] + bqn);
      }
    }
  }
#pragma unroll
  for (int it = 0; it < 16; ++it) {
    int idx = it * ATHREADS + tid;
    int r = idx >> 6, c = (idx & 63) << 2;
    s16x4 o;
    o[0] = f2bf(ld[it].x); o[1] = f2bf(ld[it].y);
    o[2] = f2bf(ld[it].z); o[3] = f2bf(ld[it].w);
    *(s16x4*)(Tbuf + swz(r, c)) = o;
  }
  __syncthreads();

  // unpack packed q (compile-time indices in unrolled loops)
#define QF(m, n, j) bf2f((short)(((j) & 1) ? (qb[m][n][(j) >> 1] >> 16) \
                                           : (qb[m][n][(j) >> 1] & 0xffffu)))

  // ---- P2: issue src loads; K_dst scores -> sc; V_dst (held in regs) ----
#pragma unroll
  for (int it = 0; it < 16; ++it) {
    int idx = it * ATHREADS + tid;
    ld[it] = *(const float4*)(st + (idx >> 6) * 256 + ((idx & 63) << 2));
  }
  {
    f32x4 ka[8][2];
#pragma unroll
    for (int m = 0; m < 8; ++m)
#pragma unroll
      for (int n = 0; n < 2; ++n) ka[m][n] = (f32x4){0.f, 0.f, 0.f, 0.f};
    gemmT<8, 2>(Tbuf, WkT, 256, cw, 0, li, hi, ka);
#pragma unroll
    for (int m = 0; m < 8; ++m)
#pragma unroll
      for (int j = 0; j < 4; ++j) {
        float pr = red16(QF(m, 0, j) * ka[m][0][j] + QF(m, 1, j) * ka[m][1][j]);
        if (li == 0) sc[w * 128 + 16 * m + 4 * hi + j] = pr;
      }
  }
  f32x4 vd[8][2];
#pragma unroll
  for (int m = 0; m < 8; ++m)
#pragma unroll
    for (int n = 0; n < 2; ++n) vd[m][n] = (f32x4){0.f, 0.f, 0.f, 0.f};
  gemmT<8, 2>(Tbuf, WvT, 256, cw, 0, li, hi, vd);
  __syncthreads();                 // all waves done reading dst
#pragma unroll
  for (int it = 0; it < 16; ++it) {
    int idx = it * ATHREADS + tid;
    int r = idx >> 6, c = (idx & 63) << 2;
    s16x4 o;
    o[0] = f2bf(ld[it].x); o[1] = f2bf(ld[it].y);
    o[2] = f2bf(ld[it].z); o[3] = f2bf(ld[it].w);
    *(s16x4*)(Tbuf + swz(r, c)) = o;
  }
  __syncthreads();

  // ---- P3: K_src scores -> weights; V_src; combine; ctx -> Tbuf ----
  {
    f32x4 ka[8][2];
#pragma unroll
    for (int m = 0; m < 8; ++m)
#pragma unroll
      for (int n = 0; n < 2; ++n) ka[m][n] = (f32x4){0.f, 0.f, 0.f, 0.f};
    gemmT<8, 2>(Tbuf, WkT, 256, cw, 0, li, hi, ka);
#pragma unroll
    for (int m = 0; m < 8; ++m)
#pragma unroll
      for (int j = 0; j < 4; ++j) {
        float ps = red16(QF(m, 0, j) * ka[m][0][j] + QF(m, 1, j) * ka[m][1][j]);
        int r = 16 * m + 4 * hi + j;
        float pdv = sc[w * 128 + r];                  // lockstep-safe
        float awv = 1.f / (1.f + expf(pdv - ps));     // weight on V_src
        if (li == 0) sc[w * 128 + r] = awv;
      }
  }
  {
    f32x4 vs[8][2];
#pragma unroll
    for (int m = 0; m < 8; ++m)
#pragma unroll
      for (int n = 0; n < 2; ++n) vs[m][n] = (f32x4){0.f, 0.f, 0.f, 0.f};
    gemmT<8, 2>(Tbuf, WvT, 256, cw, 0, li, hi, vs);
#pragma unroll
    for (int n = 0; n < 2; ++n) {
      float bvn = bv[cw + 16 * n + li];
#pragma unroll
      for (int m = 0; m < 8; ++m)
#pragma unroll
        for (int j = 0; j < 4; ++j) {
          float a = sc[w * 128 + 16 * m + 4 * hi + j];
          vs[m][n][j] = a * vs[m][n][j] + (1.f - a) * vd[m][n][j] + bvn;
        }
    }
    __syncthreads();               // all waves done reading src
#pragma unroll
    for (int m = 0; m < 8; ++m)
#pragma unroll
      for (int n = 0; n < 2; ++n)
#pragma unroll
        for (int j = 0; j < 4; ++j)
          *(short*)(Tbuf + swz(16 * m + 4 * hi + j, cw + 16 * n + li)) = f2bf(vs[m][n][j]);
  }
  __syncthreads();

  // ---- P4: O-proj + bo + x residual (Cbuf) + LN1 -> h into Cbuf ----
  {
    f32x4 oa[8][2];
#pragma unroll
    for (int m = 0; m < 8; ++m)
#pragma unroll
      for (int n = 0; n < 2; ++n) oa[m][n] = (f32x4){0.f, 0.f, 0.f, 0.f};
    gemmT<8, 2>(Tbuf, WoT, 256, cw, 0, li, hi, oa);
#pragma unroll
    for (int n = 0; n < 2; ++n) {
      float bon = bo[cw + 16 * n + li];
#pragma unroll
      for (int m = 0; m < 8; ++m)
#pragma unroll
        for (int j = 0; j < 4; ++j) {
          int r = 16 * m + 4 * hi + j;
          float xv = bf2f(*(short*)(Cbuf + swz(r, cw + 16 * n + li)));
          oa[m][n][j] += bon + xv;
        }
    }
    // LN1 partials
#pragma unroll
    for (int m = 0; m < 8; ++m)
#pragma unroll
      for (int j = 0; j < 4; ++j) {
        int r = 16 * m + 4 * hi + j;
        float sv = oa[m][0][j] + oa[m][1][j];
        float qv = oa[m][0][j] * oa[m][0][j] + oa[m][1][j] * oa[m][1][j];
        float s = red16(sv);
        float q = red16(qv);
        if (li == 0) { scrP[(w * 128 + r) * 2] = s; scrP[(w * 128 + r) * 2 + 1] = q; }
      }
    __syncthreads();
    if (tid < ABM) {
      float S = 0.f, Q = 0.f;
#pragma unroll
      for (int ww = 0; ww < 8; ++ww) {
        S += scrP[(ww * 128 + tid) * 2];
        Q += scrP[(ww * 128 + tid) * 2 + 1];
      }
      float mean = S * (1.f / 256.f);
      float var  = Q * (1.f / 256.f) - mean * mean;
      scrM[tid * 2] = mean;
      scrM[tid * 2 + 1] = rsqrtf(var + 1e-5f);
    }
    __syncthreads();
#pragma unroll
    for (int n = 0; n < 2; ++n) {
      float g1n = g1[cw + 16 * n + li];
      float b1n = be1[cw + 16 * n + li];
#pragma unroll
      for (int m = 0; m < 8; ++m)
#pragma unroll
        for (int j = 0; j < 4; ++j) {
          int r = 16 * m + 4 * hi + j;
          float mean = scrM[r * 2], rs = scrM[r * 2 + 1];
          *(short*)(Cbuf + swz(r, cw + 16 * n + li)) =
              f2bf((oa[m][n][j] - mean) * rs * g1n + b1n);
        }
    }
  }
  __syncthreads();

  // ---- coalesced bf16 h store (128 rows) ----
  {
    short* hrow = hout + row0 * 256;
#pragma unroll
    for (int t = 0; t < 8; ++t) {
      int idx = t * ATHREADS + tid;      // 0..4095 16B slots
      int r = idx >> 5, c16 = idx & 31;
      bf16x8 v = *(bf16x8*)(Cbuf + r * 512 + ((c16 * 16) ^ ((r & 7) << 4)));
      *(bf16x8*)(hrow + r * 256 + c16 * 8) = v;
    }
  }
#undef QF
}

// ================= kernel B: FFN + residual + LN2 -> out (f32) =================
// BM=128, 512 threads / 8 waves x 32 out-cols, MF=8. 1 block/CU at 256-reg budget.
__global__ __launch_bounds__(FTHREADS, 2)
void ffn_ln2(const short* __restrict__ hin, const float* __restrict__ b1,
             const float* __restrict__ b2,
             const float* __restrict__ g2, const float* __restrict__ be2,
             const short* __restrict__ wt, float* __restrict__ out) {
  extern __shared__ char sm[];
  char* Cbuf = sm;                        // h tile [128][256] bf16 (64K) -> out stage
  char* Hbuf = sm + 65536;                // hid chunk [128][256] bf16 (64K) -> LN scratch
  float* scrP = (float*)Hbuf;             // LN2 partials [8][128][2] (8K, aliases Hbuf)
  float* scrM = (float*)(Hbuf + 8192);    // LN2 mean/rstd [128][2] (1K)

  const short* W1T = wt + 262144;
  const short* W2T = wt + 524288;

  const int tid  = threadIdx.x;
  const int w    = tid >> 6;              // 0..7
  const int lane = tid & 63;
  const int li   = lane & 15;
  const int hi   = lane >> 4;
  const int cw   = w * 32;                // wave output col slice (32 cols)
  const size_t row0 = (size_t)blockIdx.x * FBM;

  // ---- stage h (bf16) -> Cbuf swizzled (128 rows) ----
  {
    const short* hrow = hin + row0 * 256;
#pragma unroll
    for (int t = 0; t < 8; ++t) {
      int idx = t * FTHREADS + tid;     // 0..4095 16B slots
      int r = idx >> 5, c16 = idx & 31;
      bf16x8 v = *(const bf16x8*)(hrow + r * 256 + c16 * 8);
      *(bf16x8*)(Cbuf + r * 512 + ((c16 * 16) ^ ((r & 7) << 4))) = v;
    }
  }
  __syncthreads();

  // ---- FFN: 4 chunks of 256 hidden; wave does 32 hidden cols (W1) then
  //      32 output cols (W2), MF=8 rows ----
  f32x4 a2[8][2];
#pragma unroll
  for (int m = 0; m < 8; ++m)
#pragma unroll
    for (int n = 0; n < 2; ++n) a2[m][n] = (f32x4){0.f, 0.f, 0.f, 0.f};
#pragma unroll 1
  for (int c = 0; c < 4; ++c) {
    f32x4 a1[8][2];
#pragma unroll
    for (int m = 0; m < 8; ++m)
#pragma unroll
      for (int n = 0; n < 2; ++n) a1[m][n] = (f32x4){0.f, 0.f, 0.f, 0.f};
    gemmT<8, 2, 256, 512>(Cbuf, W1T, 256, 256 * c + cw, 0, li, hi, a1);
#pragma unroll
    for (int n = 0; n < 2; ++n) {
      float b1n = b1[256 * c + cw + 16 * n + li];
      int lc = cw + 16 * n + li;        // local col in 256-chunk
#pragma unroll
      for (int m = 0; m < 8; ++m)
#pragma unroll
        for (int j = 0; j < 4; ++j) {
          int r = 16 * m + 4 * hi + j;
          *(short*)(Hbuf + swzR<512>(r, lc)) = f2bf(fmaxf(a1[m][n][j] + b1n, 0.f));
        }
    }
    __syncthreads();
    gemmT<8, 2, 256, 512>(Hbuf, W2T, 1024, cw, 256 * c, li, hi, a2);
    __syncthreads();
  }

  // ---- +b2 + h residual (this wave's 32 cols, 128 rows) ----
  {
#pragma unroll
    for (int n = 0; n < 2; ++n) {
      float b2n = b2[cw + 16 * n + li];
#pragma unroll
      for (int m = 0; m < 8; ++m)
#pragma unroll
        for (int j = 0; j < 4; ++j) {
          int r = 16 * m + 4 * hi + j;
          a2[m][n][j] += b2n + bf2f(*(short*)(Cbuf + swz(r, cw + 16 * n + li)));
        }
    }
  }
  __syncthreads();   // Hbuf reads done (last W2) before scrP overwrites it

  // ---- LN2 partials (per wave, 32 cols, 128 rows) ----
#pragma unroll
  for (int m = 0; m < 8; ++m)
#pragma unroll
    for (int j = 0; j < 4; ++j) {
      int r = 16 * m + 4 * hi + j;
      float sv = a2[m][0][j] + a2[m][1][j];
      float qv = a2[m][0][j] * a2[m][0][j] + a2[m][1][j] * a2[m][1][j];
      float s = red16(sv);
      float q = red16(qv);
      if (li == 0) { scrP[(w * 128 + r) * 2] = s; scrP[(w * 128 + r) * 2 + 1] = q; }
    }
  __syncthreads();
  if (tid < FBM) {
    float S = 0.f, Q = 0.f;
#pragma unroll
    for (int ww = 0; ww < 8; ++ww) {
      S += scrP[(ww * 128 + tid) * 2];
      Q += scrP[(ww * 128 + tid) * 2 + 1];
    }
    float mean = S * (1.f / 256.f);
    float var  = Q * (1.f / 256.f) - mean * mean;
    scrM[tid * 2] = mean;
    scrM[tid * 2 + 1] = rsqrtf(var + 1e-5f);
  }
  __syncthreads();

  // ---- LN2 apply + coalesced store via Cbuf f32 stage (4 quarters of 32 rows) ----
  {
    float g2n[2], b2n[2];
#pragma unroll
    for (int n = 0; n < 2; ++n) {
      g2n[n] = g2[cw + 16 * n + li];
      b2n[n] = be2[cw + 16 * n + li];
    }
    float* orow = out + row0 * 256;
#pragma unroll
    for (int hf = 0; hf < 4; ++hf) {
#pragma unroll
      for (int m2 = 0; m2 < 2; ++m2) {
        int m = 2 * hf + m2;
#pragma unroll
        for (int n = 0; n < 2; ++n)
#pragma unroll
          for (int j = 0; j < 4; ++j) {
            int r = 16 * m + 4 * hi + j;
            float mean = scrM[r * 2], rs = scrM[r * 2 + 1];
            int rr = r - 32 * hf;
            *(float*)(Cbuf + rr * 1024 + (((cw + 16 * n + li) * 4) ^ ((rr & 7) << 4)))
                = (a2[m][n][j] - mean) * rs * g2n[n] + b2n[n];
          }
      }
      __syncthreads();
#pragma unroll
      for (int t = 0; t < 4; ++t) {
        int idx = t * FTHREADS + tid;          // 0..2047 float4 slots
        int r = idx >> 6, c4 = idx & 63;       // r 0..31
        f32x4 v = *(f32x4*)(Cbuf + r * 1024 + ((c4 * 16) ^ ((r & 7) << 4)));
        *(f32x4*)(orow + (hf * 32 + r) * 256 + c4 * 4) = v;
      }
      __syncthreads();
    }
  }
}

extern "C" void kernel_launch(void* const* d_in, const int* in_sizes, int n_in,
                              void* d_out, int out_size, void* d_ws, size_t ws_size,
                              hipStream_t stream) {
  const float* x   = (const float*)d_in[0];
  const float* sx  = (const float*)d_in[1];
  const float* dx  = (const float*)d_in[2];
  const float* Wq  = (const float*)d_in[3];
  const float* bq  = (const float*)d_in[4];
  const float* Wk  = (const float*)d_in[5];
  const float* Wv  = (const float*)d_in[7];
  const float* bv  = (const float*)d_in[8];
  const float* Wo  = (const float*)d_in[9];
  const float* bo  = (const float*)d_in[10];
  const float* W1  = (const float*)d_in[11];
  const float* b1  = (const float*)d_in[12];
  const float* W2  = (const float*)d_in[13];
  const float* b2  = (const float*)d_in[14];
  const float* g1  = (const float*)d_in[15];
  const float* be1 = (const float*)d_in[16];
  const float* g2  = (const float*)d_in[17];
  const float* be2 = (const float*)d_in[18];
  short* wt = (short*)d_ws;
  short* hbuf = wt + 786432;

  prep<<<dim3(1536), dim3(512), 0, stream>>>(Wq, Wk, Wv, Wo, W1, W2, wt);
  attn_ln1<<<dim3(NROWS / ABM), dim3(ATHREADS), LDSB_A, stream>>>(
      x, sx, dx, bq, bv, bo, g1, be1, wt, hbuf);
  ffn_ln2<<<dim3(NROWS / FBM), dim3(FTHREADS), LDSB_B, stream>>>(
      hbuf, b1, b2, g2, be2, wt, (float*)d_out);
}

// Round 19
// 1064.489 us; speedup vs baseline: 1.0297x; 1.0297x over previous
//
#include <hip/hip_runtime.h>
#include <hip/hip_bf16.h>
#include <math.h>

#define NROWS   262144
#define ABM     128                                     // attn rows/block
#define FBM     128                                     // ffn rows/block
#define NTHR    512
#define LDSB_A  (65536 + 65536 + 4096 + 8192 + 1024)    // attn: 141K, 1 block/CU
#define LDSB_B  (65536 + 65536)                         // ffn: Cbuf 64K + Hbuf 64K

using bf16x8 = __attribute__((ext_vector_type(8))) short;
using s16x4  = __attribute__((ext_vector_type(4))) short;
using f32x4  = __attribute__((ext_vector_type(4))) float;

__device__ __forceinline__ short f2bf(float f) {
  __hip_bfloat16 h = __float2bfloat16(f);
  return __builtin_bit_cast(short, h);
}
__device__ __forceinline__ float bf2f(short s) {
  __hip_bfloat16 h = __builtin_bit_cast(__hip_bfloat16, s);
  return __bfloat162float(h);
}
__device__ __forceinline__ unsigned pack2(float a, float b) {
  return (unsigned)(unsigned short)f2bf(a) | ((unsigned)(unsigned short)f2bf(b) << 16);
}
// XOR-swizzled byte offset into a bf16 LDS tile with row stride RSTR bytes
template <int RSTR>
__device__ __forceinline__ int swzR(int row, int col) {
  return row * RSTR + ((col * 2) ^ ((row & 7) << 4));
}
__device__ __forceinline__ int swz(int row, int col) {   // 256-col tile (512B rows)
  return swzR<512>(row, col);
}

__device__ __forceinline__ float red16(float p) {
  p += __shfl_xor(p, 1, 64);
  p += __shfl_xor(p, 2, 64);
  p += __shfl_xor(p, 4, 64);
  p += __shfl_xor(p, 8, 64);
  return p;
}

// half-tile (64 rows) staging: issue 8 float4 loads / convert+write to LDS
__device__ __forceinline__ void stage_issue(float4 (&ld)[8],
                                            const float* __restrict__ g,
                                            int tid, int half) {
#pragma unroll
  for (int it = 0; it < 8; ++it) {
    int idx = (half * 8 + it) * NTHR + tid;   // rows 64*half .. 64*half+63
    ld[it] = *(const float4*)(g + (idx >> 6) * 256 + ((idx & 63) << 2));
  }
}
__device__ __forceinline__ void stage_write(float4 (&ld)[8],
                                            char* __restrict__ buf,
                                            int tid, int half) {
#pragma unroll
  for (int it = 0; it < 8; ++it) {
    int idx = (half * 8 + it) * NTHR + tid;
    int r = idx >> 6, c = (idx & 63) << 2;
    s16x4 o;
    o[0] = f2bf(ld[it].x); o[1] = f2bf(ld[it].y);
    o[2] = f2bf(ld[it].z); o[3] = f2bf(ld[it].w);
    *(s16x4*)(buf + swz(r, c)) = o;
  }
}

// C[MF*16 rows x NF*16 cols] += A_lds[.., akoff..akoff+KLEN] @ WT[cols][koff..]
template <int MF, int NF, int KLEN = 256, int RSTR = 512>
__device__ __forceinline__ void gemmT(const char* __restrict__ Abuf,
                                      const short* __restrict__ WT, int Kw,
                                      int col0, int koff, int akoff, int li, int hi,
                                      f32x4 (&acc)[MF][NF]) {
  const short* wp[NF];
#pragma unroll
  for (int n = 0; n < NF; ++n)
    wp[n] = WT + (size_t)(col0 + 16 * n + li) * Kw + koff + hi * 8;
#pragma unroll 2
  for (int kk = 0; kk < KLEN; kk += 32) {
    int ka = akoff + kk + hi * 8;
    bf16x8 b[NF];
#pragma unroll
    for (int n = 0; n < NF; ++n) b[n] = *(const bf16x8*)(wp[n] + kk);
    bf16x8 a[MF];
#pragma unroll
    for (int m = 0; m < MF; ++m)
      a[m] = *(const bf16x8*)(Abuf + swzR<RSTR>(16 * m + li, ka));
#pragma unroll
    for (int m = 0; m < MF; ++m)
#pragma unroll
      for (int n = 0; n < NF; ++n)
        acc[m][n] = __builtin_amdgcn_mfma_f32_16x16x32_bf16(a[m], b[n], acc[m][n], 0, 0, 0);
  }
}

// transpose + bf16-convert all weights (Wq pre-scaled by 1/sqrt(DH)):
// WqT,WkT,WvT,WoT: [256][256]; W1T: [1024][256]; W2T: [256][1024]
__global__ void prep(const float* __restrict__ Wq, const float* __restrict__ Wk,
                     const float* __restrict__ Wv, const float* __restrict__ Wo,
                     const float* __restrict__ W1, const float* __restrict__ W2,
                     short* __restrict__ wt) {
  int idx = blockIdx.x * blockDim.x + threadIdx.x;  // 0..786431
  if (idx < 262144) {
    int m = idx >> 16;
    const float* W = (m == 0) ? Wq : (m == 1) ? Wk : (m == 2) ? Wv : Wo;
    float s = (m == 0) ? 0.17677669529663687f : 1.0f;
    int l = idx & 65535;
    int n = l >> 8, k = l & 255;
    wt[idx] = f2bf(W[k * 256 + n] * s);
  } else if (idx < 524288) {
    int l = idx - 262144;
    int n = l >> 8, k = l & 255;
    wt[idx] = f2bf(W1[k * 1024 + n]);
  } else {
    int l = idx - 524288;
    int n = l >> 10, k = l & 1023;
    wt[idx] = f2bf(W2[k * 256 + n]);
  }
}

// ================= kernel A: attention + O-proj + LN1 -> h (bf16) =================
// BM=128, 512 threads / 8 waves; wave w owns head w (32 cols), MF=8, NF=2.
// Half-tile reg staging (ld[8]) keeps arch VGPR <= 128.
__global__ __launch_bounds__(NTHR, 2)
void attn_ln1(const float* __restrict__ x, const float* __restrict__ sx,
              const float* __restrict__ dx,
              const float* __restrict__ bq, const float* __restrict__ bv,
              const float* __restrict__ bo,
              const float* __restrict__ g1, const float* __restrict__ be1,
              const short* __restrict__ wt, short* __restrict__ hout) {
  extern __shared__ char sm[];
  char*  Cbuf = sm;                        // x tile [128][256] (persistent) -> h
  char*  Tbuf = sm + 65536;                // dst -> src -> ctx
  float* sc   = (float*)(sm + 131072);     // [8 waves][128 rows] scores/weights (4K)
  float* scrP = (float*)(sm + 135168);     // LN1 partials [8][128][2] (8K)
  float* scrM = (float*)(sm + 143360);     // LN1 mean/rstd [128][2] (1K)

  const short* WqT = wt;
  const short* WkT = wt + 65536;
  const short* WvT = wt + 131072;
  const short* WoT = wt + 196608;

  const int tid  = threadIdx.x;
  const int w    = tid >> 6;               // 0..7 (= head)
  const int lane = tid & 63;
  const int li   = lane & 15;
  const int hi   = lane >> 4;
  const int cw   = w * 32;                 // wave col slice (1 head)
  const size_t row0 = (size_t)blockIdx.x * ABM;

  const float* xt = x  + row0 * 256;
  const float* st = sx + row0 * 256;
  const float* dt = dx + row0 * 256;

  float4 ld[8];

  // ---- P0: stage x -> Cbuf (persistent) ----
  stage_issue(ld, xt, tid, 0);
  stage_write(ld, Cbuf, tid, 0);
  stage_issue(ld, xt, tid, 1);
  stage_write(ld, Cbuf, tid, 1);
  __syncthreads();

  // ---- P1: Q gemm (K-split) hides both dst half-stages ----
  unsigned qb[8][2][2];
  {
    f32x4 qa[8][2];
#pragma unroll
    for (int m = 0; m < 8; ++m)
#pragma unroll
      for (int n = 0; n < 2; ++n) qa[m][n] = (f32x4){0.f, 0.f, 0.f, 0.f};
    stage_issue(ld, dt, tid, 0);
    gemmT<8, 2, 128>(Cbuf, WqT, 256, cw, 0, 0, li, hi, qa);
    stage_write(ld, Tbuf, tid, 0);
    stage_issue(ld, dt, tid, 1);
    gemmT<8, 2, 128>(Cbuf, WqT, 256, cw, 128, 128, li, hi, qa);
    stage_write(ld, Tbuf, tid, 1);
    const float scl = 0.17677669529663687f;
#pragma unroll
    for (int n = 0; n < 2; ++n) {
      float bqn = bq[cw + 16 * n + li] * scl;
#pragma unroll
      for (int m = 0; m < 8; ++m) {
        qb[m][n][0] = pack2(qa[m][n][0] + bqn, qa[m][n][1] + bqn);
        qb[m][n][1] = pack2(qa[m][n][2] + bqn, qa[m][n][3] + bqn);
      }
    }
  }
  __syncthreads();

  // unpack packed q (compile-time indices in unrolled loops)
#define QF(m, n, j) bf2f((short)(((j) & 1) ? (qb[m][n][(j) >> 1] >> 16) \
                                           : (qb[m][n][(j) >> 1] & 0xffffu)))

  // ---- P2: K_dst scores -> sc; V_dst -> vd; src-lo in flight ----
  f32x4 vd[8][2];
  {
    f32x4 ka[8][2];
#pragma unroll
    for (int m = 0; m < 8; ++m)
#pragma unroll
      for (int n = 0; n < 2; ++n) ka[m][n] = (f32x4){0.f, 0.f, 0.f, 0.f};
    stage_issue(ld, st, tid, 0);           // src-lo hides under dst gemms
    gemmT<8, 2>(Tbuf, WkT, 256, cw, 0, 0, li, hi, ka);
#pragma unroll
    for (int m = 0; m < 8; ++m)
#pragma unroll
      for (int j = 0; j < 4; ++j) {
        float pr = red16(QF(m, 0, j) * ka[m][0][j] + QF(m, 1, j) * ka[m][1][j]);
        if (li == 0) sc[w * 128 + 16 * m + 4 * hi + j] = pr;
      }
#pragma unroll
    for (int m = 0; m < 8; ++m)
#pragma unroll
      for (int n = 0; n < 2; ++n) vd[m][n] = (f32x4){0.f, 0.f, 0.f, 0.f};
    gemmT<8, 2>(Tbuf, WvT, 256, cw, 0, 0, li, hi, vd);
  }
  __syncthreads();                         // all waves done reading dst
  stage_write(ld, Tbuf, tid, 0);           // src-lo -> Tbuf
  stage_issue(ld, st, tid, 1);
  stage_write(ld, Tbuf, tid, 1);           // src-hi (one exposed latency)
  __syncthreads();

  // ---- P3: K_src scores -> weights; V_src; combine; ctx -> Tbuf ----
  {
    f32x4 ka[8][2];
#pragma unroll
    for (int m = 0; m < 8; ++m)
#pragma unroll
      for (int n = 0; n < 2; ++n) ka[m][n] = (f32x4){0.f, 0.f, 0.f, 0.f};
    gemmT<8, 2>(Tbuf, WkT, 256, cw, 0, 0, li, hi, ka);
#pragma unroll
    for (int m = 0; m < 8; ++m)
#pragma unroll
      for (int j = 0; j < 4; ++j) {
        float ps = red16(QF(m, 0, j) * ka[m][0][j] + QF(m, 1, j) * ka[m][1][j]);
        int r = 16 * m + 4 * hi + j;
        float pdv = sc[w * 128 + r];                  // lockstep-safe
        float awv = 1.f / (1.f + expf(pdv - ps));     // weight on V_src
        if (li == 0) sc[w * 128 + r] = awv;
      }
  }
  {
    f32x4 vs[8][2];
#pragma unroll
    for (int m = 0; m < 8; ++m)
#pragma unroll
      for (int n = 0; n < 2; ++n) vs[m][n] = (f32x4){0.f, 0.f, 0.f, 0.f};
    gemmT<8, 2>(Tbuf, WvT, 256, cw, 0, 0, li, hi, vs);
#pragma unroll
    for (int n = 0; n < 2; ++n) {
      float bvn = bv[cw + 16 * n + li];
#pragma unroll
      for (int m = 0; m < 8; ++m)
#pragma unroll
        for (int j = 0; j < 4; ++j) {
          float a = sc[w * 128 + 16 * m + 4 * hi + j];
          vs[m][n][j] = a * vs[m][n][j] + (1.f - a) * vd[m][n][j] + bvn;
        }
    }
    __syncthreads();               // all waves done reading src
#pragma unroll
    for (int m = 0; m < 8; ++m)
#pragma unroll
      for (int n = 0; n < 2; ++n)
#pragma unroll
        for (int j = 0; j < 4; ++j)
          *(short*)(Tbuf + swz(16 * m + 4 * hi + j, cw + 16 * n + li)) = f2bf(vs[m][n][j]);
  }
  __syncthreads();

  // ---- P4: O-proj + bo + x residual (Cbuf) + LN1 -> h into Cbuf ----
  {
    f32x4 oa[8][2];
#pragma unroll
    for (int m = 0; m < 8; ++m)
#pragma unroll
      for (int n = 0; n < 2; ++n) oa[m][n] = (f32x4){0.f, 0.f, 0.f, 0.f};
    gemmT<8, 2>(Tbuf, WoT, 256, cw, 0, 0, li, hi, oa);
#pragma unroll
    for (int n = 0; n < 2; ++n) {
      float bon = bo[cw + 16 * n + li];
#pragma unroll
      for (int m = 0; m < 8; ++m)
#pragma unroll
        for (int j = 0; j < 4; ++j) {
          int r = 16 * m + 4 * hi + j;
          float xv = bf2f(*(short*)(Cbuf + swz(r, cw + 16 * n + li)));
          oa[m][n][j] += bon + xv;
        }
    }
    // LN1 partials
#pragma unroll
    for (int m = 0; m < 8; ++m)
#pragma unroll
      for (int j = 0; j < 4; ++j) {
        int r = 16 * m + 4 * hi + j;
        float sv = oa[m][0][j] + oa[m][1][j];
        float qv = oa[m][0][j] * oa[m][0][j] + oa[m][1][j] * oa[m][1][j];
        float s = red16(sv);
        float q = red16(qv);
        if (li == 0) { scrP[(w * 128 + r) * 2] = s; scrP[(w * 128 + r) * 2 + 1] = q; }
      }
    __syncthreads();
    if (tid < ABM) {
      float S = 0.f, Q = 0.f;
#pragma unroll
      for (int ww = 0; ww < 8; ++ww) {
        S += scrP[(ww * 128 + tid) * 2];
        Q += scrP[(ww * 128 + tid) * 2 + 1];
      }
      float mean = S * (1.f / 256.f);
      float var  = Q * (1.f / 256.f) - mean * mean;
      scrM[tid * 2] = mean;
      scrM[tid * 2 + 1] = rsqrtf(var + 1e-5f);
    }
    __syncthreads();
#pragma unroll
    for (int n = 0; n < 2; ++n) {
      float g1n = g1[cw + 16 * n + li];
      float b1n = be1[cw + 16 * n + li];
#pragma unroll
      for (int m = 0; m < 8; ++m)
#pragma unroll
        for (int j = 0; j < 4; ++j) {
          int r = 16 * m + 4 * hi + j;
          float mean = scrM[r * 2], rs = scrM[r * 2 + 1];
          *(short*)(Cbuf + swz(r, cw + 16 * n + li)) =
              f2bf((oa[m][n][j] - mean) * rs * g1n + b1n);
        }
    }
  }
  __syncthreads();

  // ---- coalesced bf16 h store (128 rows) ----
  {
    short* hrow = hout + row0 * 256;
#pragma unroll
    for (int t = 0; t < 8; ++t) {
      int idx = t * NTHR + tid;          // 0..4095 16B slots
      int r = idx >> 5, c16 = idx & 31;
      bf16x8 v = *(bf16x8*)(Cbuf + r * 512 + ((c16 * 16) ^ ((r & 7) << 4)));
      *(bf16x8*)(hrow + r * 256 + c16 * 8) = v;
    }
  }
#undef QF
}

// ================= kernel B: FFN + residual + LN2 -> out (f32) =================
// BM=128, 512 threads / 8 waves x 32 out-cols, MF=8. 1 block/CU at 256-reg budget.
__global__ __launch_bounds__(NTHR, 2)
void ffn_ln2(const short* __restrict__ hin, const float* __restrict__ b1,
             const float* __restrict__ b2,
             const float* __restrict__ g2, const float* __restrict__ be2,
             const short* __restrict__ wt, float* __restrict__ out) {
  extern __shared__ char sm[];
  char* Cbuf = sm;                        // h tile [128][256] bf16 (64K) -> out stage
  char* Hbuf = sm + 65536;                // hid chunk [128][256] bf16 (64K) -> LN scratch
  float* scrP = (float*)Hbuf;             // LN2 partials [8][128][2] (8K, aliases Hbuf)
  float* scrM = (float*)(Hbuf + 8192);    // LN2 mean/rstd [128][2] (1K)

  const short* W1T = wt + 262144;
  const short* W2T = wt + 524288;

  const int tid  = threadIdx.x;
  const int w    = tid >> 6;              // 0..7
  const int lane = tid & 63;
  const int li   = lane & 15;
  const int hi   = lane >> 4;
  const int cw   = w * 32;                // wave output col slice (32 cols)
  const size_t row0 = (size_t)blockIdx.x * FBM;

  // ---- stage h (bf16) -> Cbuf swizzled (128 rows) ----
  {
    const short* hrow = hin + row0 * 256;
#pragma unroll
    for (int t = 0; t < 8; ++t) {
      int idx = t * NTHR + tid;         // 0..4095 16B slots
      int r = idx >> 5, c16 = idx & 31;
      bf16x8 v = *(const bf16x8*)(hrow + r * 256 + c16 * 8);
      *(bf16x8*)(Cbuf + r * 512 + ((c16 * 16) ^ ((r & 7) << 4))) = v;
    }
  }
  __syncthreads();

  // ---- FFN: 4 chunks of 256 hidden; wave does 32 hidden cols (W1) then
  //      32 output cols (W2), MF=8 rows ----
  f32x4 a2[8][2];
#pragma unroll
  for (int m = 0; m < 8; ++m)
#pragma unroll
    for (int n = 0; n < 2; ++n) a2[m][n] = (f32x4){0.f, 0.f, 0.f, 0.f};
#pragma unroll 1
  for (int c = 0; c < 4; ++c) {
    f32x4 a1[8][2];
#pragma unroll
    for (int m = 0; m < 8; ++m)
#pragma unroll
      for (int n = 0; n < 2; ++n) a1[m][n] = (f32x4){0.f, 0.f, 0.f, 0.f};
    gemmT<8, 2, 256, 512>(Cbuf, W1T, 256, 256 * c + cw, 0, 0, li, hi, a1);
#pragma unroll
    for (int n = 0; n < 2; ++n) {
      float b1n = b1[256 * c + cw + 16 * n + li];
      int lc = cw + 16 * n + li;        // local col in 256-chunk
#pragma unroll
      for (int m = 0; m < 8; ++m)
#pragma unroll
        for (int j = 0; j < 4; ++j) {
          int r = 16 * m + 4 * hi + j;
          *(short*)(Hbuf + swzR<512>(r, lc)) = f2bf(fmaxf(a1[m][n][j] + b1n, 0.f));
        }
    }
    __syncthreads();
    gemmT<8, 2, 256, 512>(Hbuf, W2T, 1024, cw, 256 * c, 0, li, hi, a2);
    __syncthreads();
  }

  // ---- +b2 + h residual (this wave's 32 cols, 128 rows) ----
  {
#pragma unroll
    for (int n = 0; n < 2; ++n) {
      float b2n = b2[cw + 16 * n + li];
#pragma unroll
      for (int m = 0; m < 8; ++m)
#pragma unroll
        for (int j = 0; j < 4; ++j) {
          int r = 16 * m + 4 * hi + j;
          a2[m][n][j] += b2n + bf2f(*(short*)(Cbuf + swz(r, cw + 16 * n + li)));
        }
    }
  }
  __syncthreads();   // Hbuf reads done (last W2) before scrP overwrites it

  // ---- LN2 partials (per wave, 32 cols, 128 rows) ----
#pragma unroll
  for (int m = 0; m < 8; ++m)
#pragma unroll
    for (int j = 0; j < 4; ++j) {
      int r = 16 * m + 4 * hi + j;
      float sv = a2[m][0][j] + a2[m][1][j];
      float qv = a2[m][0][j] * a2[m][0][j] + a2[m][1][j] * a2[m][1][j];
      float s = red16(sv);
      float q = red16(qv);
      if (li == 0) { scrP[(w * 128 + r) * 2] = s; scrP[(w * 128 + r) * 2 + 1] = q; }
    }
  __syncthreads();
  if (tid < FBM) {
    float S = 0.f, Q = 0.f;
#pragma unroll
    for (int ww = 0; ww < 8; ++ww) {
      S += scrP[(ww * 128 + tid) * 2];
      Q += scrP[(ww * 128 + tid) * 2 + 1];
    }
    float mean = S * (1.f / 256.f);
    float var  = Q * (1.f / 256.f) - mean * mean;
    scrM[tid * 2] = mean;
    scrM[tid * 2 + 1] = rsqrtf(var + 1e-5f);
  }
  __syncthreads();

  // ---- LN2 apply + coalesced store via Cbuf f32 stage (4 quarters of 32 rows) ----
  {
    float g2n[2], b2n[2];
#pragma unroll
    for (int n = 0; n < 2; ++n) {
      g2n[n] = g2[cw + 16 * n + li];
      b2n[n] = be2[cw + 16 * n + li];
    }
    float* orow = out + row0 * 256;
#pragma unroll
    for (int hf = 0; hf < 4; ++hf) {
#pragma unroll
      for (int m2 = 0; m2 < 2; ++m2) {
        int m = 2 * hf + m2;
#pragma unroll
        for (int n = 0; n < 2; ++n)
#pragma unroll
          for (int j = 0; j < 4; ++j) {
            int r = 16 * m + 4 * hi + j;
            float mean = scrM[r * 2], rs = scrM[r * 2 + 1];
            int rr = r - 32 * hf;
            *(float*)(Cbuf + rr * 1024 + (((cw + 16 * n + li) * 4) ^ ((rr & 7) << 4)))
                = (a2[m][n][j] - mean) * rs * g2n[n] + b2n[n];
          }
      }
      __syncthreads();
#pragma unroll
      for (int t = 0; t < 4; ++t) {
        int idx = t * NTHR + tid;              // 0..2047 float4 slots
        int r = idx >> 6, c4 = idx & 63;       // r 0..31
        f32x4 v = *(f32x4*)(Cbuf + r * 1024 + ((c4 * 16) ^ ((r & 7) << 4)));
        *(f32x4*)(orow + (hf * 32 + r) * 256 + c4 * 4) = v;
      }
      __syncthreads();
    }
  }
}

extern "C" void kernel_launch(void* const* d_in, const int* in_sizes, int n_in,
                              void* d_out, int out_size, void* d_ws, size_t ws_size,
                              hipStream_t stream) {
  const float* x   = (const float*)d_in[0];
  const float* sx  = (const float*)d_in[1];
  const float* dx  = (const float*)d_in[2];
  const float* Wq  = (const float*)d_in[3];
  const float* bq  = (const float*)d_in[4];
  const float* Wk  = (const float*)d_in[5];
  const float* Wv  = (const float*)d_in[7];
  const float* bv  = (const float*)d_in[8];
  const float* Wo  = (const float*)d_in[9];
  const float* bo  = (const float*)d_in[10];
  const float* W1  = (const float*)d_in[11];
  const float* b1  = (const float*)d_in[12];
  const float* W2  = (const float*)d_in[13];
  const float* b2  = (const float*)d_in[14];
  const float* g1  = (const float*)d_in[15];
  const float* be1 = (const float*)d_in[16];
  const float* g2  = (const float*)d_in[17];
  const float* be2 = (const float*)d_in[18];
  short* wt = (short*)d_ws;
  short* hbuf = wt + 786432;

  prep<<<dim3(1536), dim3(512), 0, stream>>>(Wq, Wk, Wv, Wo, W1, W2, wt);
  attn_ln1<<<dim3(NROWS / ABM), dim3(NTHR), LDSB_A, stream>>>(
      x, sx, dx, bq, bv, bo, g1, be1, wt, hbuf);
  ffn_ln2<<<dim3(NROWS / FBM), dim3(NTHR), LDSB_B, stream>>>(
      hbuf, b1, b2, g2, be2, wt, (float*)d_out);
}